// Round 4
// baseline (31.388 us; speedup 1.0000x reference)
//
#include <hip/hip_runtime.h>
#include <math.h>

#define N 8192
#define NP 4096

// Monotone total-order key: K_k > K_j  <=>  t_k > t_j || (t_k == t_j && k < j)
// (exactly the stable descending-argsort rank predicate of jnp.argsort(-target)).
__device__ __forceinline__ unsigned int fkey(float x) {
    unsigned int u = __float_as_uint(x);
    unsigned int m = (unsigned int)((int)u >> 31) | 0x80000000u;
    return u ^ m;
}
__device__ __forceinline__ unsigned long long fullkey(float x, int k) {
    return ((unsigned long long)fkey(x) << 13) | (unsigned long long)(N - 1 - k);
}

// Kernel 1: rank via ballot+popcount (1024 waves x 8 j's each), scatter
// ea[rank]=e^p, eb[rank]=e^-p, and per-block partial of F = sum_i (f_i - f_{N-1-i})
// expressed as sum_j (rank_j < NP ? +p_j : -p_j).
__global__ void __launch_bounds__(256) rank_kernel(
    const float* __restrict__ pred,
    const float* __restrict__ target,
    float* __restrict__ ws)
{
    float* ea = ws;                          // [0, 8192)
    float* eb = ws + N;                      // [8192, 16384)
    double* part = (double*)(ws + 2 * N);    // 256 doubles

    const int t    = threadIdx.x;
    const int lane = t & 63;
    const int wv   = t >> 6;
    const int b    = blockIdx.x;
    const int wid  = b * 4 + wv;
    const int jbase = wid * 8;

    __shared__ float sWS[4];

    unsigned long long Kj[8];
    #pragma unroll
    for (int jj = 0; jj < 8; ++jj)
        Kj[jj] = fullkey(target[jbase + jj], jbase + jj);

    int cnt[8] = {0,0,0,0,0,0,0,0};

    // rotated start so the 8 XCDs pull different 1KB chunks into L2 in parallel
    const int rot = b & 31;

    // 4-deep register prefetch pipeline over the 32 k-chunks (256 floats each)
    float4 buf[4];
    #pragma unroll
    for (int p = 0; p < 4; ++p) {
        const int c = (p + rot) & 31;
        buf[p] = *reinterpret_cast<const float4*>(target + c * 256 + lane * 4);
    }

    #pragma unroll 4
    for (int it = 0; it < 32; ++it) {
        const int cchunk = (it + rot) & 31;
        const int kb = cchunk * 256 + lane * 4;
        const float4 tv = buf[it & 3];
        if (it + 4 < 32) {
            const int nc = (it + 4 + rot) & 31;
            buf[it & 3] = *reinterpret_cast<const float4*>(target + nc * 256 + lane * 4);
        }
        unsigned long long Kk[4];
        Kk[0] = fullkey(tv.x, kb);
        Kk[1] = fullkey(tv.y, kb + 1);
        Kk[2] = fullkey(tv.z, kb + 2);
        Kk[3] = fullkey(tv.w, kb + 3);
        #pragma unroll
        for (int jj = 0; jj < 8; ++jj) {
            cnt[jj] += __popcll(__ballot(Kk[0] > Kj[jj]));
            cnt[jj] += __popcll(__ballot(Kk[1] > Kj[jj]));
            cnt[jj] += __popcll(__ballot(Kk[2] > Kj[jj]));
            cnt[jj] += __popcll(__ballot(Kk[3] > Kj[jj]));
        }
    }

    // lane jj scatters element jbase+jj (cnt[] is wave-uniform)
    float sv = 0.f;
    #pragma unroll
    for (int jj = 0; jj < 8; ++jj) {
        if (lane == jj) {
            const float p = pred[jbase + jj];
            const float e = __expf(p);
            ea[cnt[jj]] = e;
            eb[cnt[jj]] = __builtin_amdgcn_rcpf(e);
            sv = (cnt[jj] < NP) ? p : -p;
        }
    }
    sv += __shfl_xor(sv, 1, 64);
    sv += __shfl_xor(sv, 2, 64);
    sv += __shfl_xor(sv, 4, 64);
    if (lane == 0) sWS[wv] = sv;
    __syncthreads();
    if (t == 0)
        part[b] = (double)(sWS[0] + sWS[1] + sWS[2] + sWS[3]);
}

// Kernel 2: closed-form loss from scattered exponentials.
//   a_i = ea_i + ea_{N-1-i},  b_i = eb_i + eb_{N-1-i}
//   E_i,G_i = suffix sums over [i, NP);  denom_i = E_i*G_i - (N-2i)  (>= 2)
//   out = sum_i log(denom_i) - F
__global__ void __launch_bounds__(1024) loss_kernel(
    const float* __restrict__ ws,
    float* __restrict__ out)
{
    const float* ea = ws;
    const float* eb = ws + N;
    const double* part = (const double*)(ws + 2 * N);

    __shared__ float sWA[16], sWB[16];
    __shared__ double sL[16];

    const int t    = threadIdx.x;
    const int lane = t & 63;
    const int wv   = t >> 6;
    const int base = 4 * t;

    const float4 af4 = *reinterpret_cast<const float4*>(ea + base);
    const float4 ar4 = *reinterpret_cast<const float4*>(ea + (N - 4 - base));
    const float4 bf4 = *reinterpret_cast<const float4*>(eb + base);
    const float4 br4 = *reinterpret_cast<const float4*>(eb + (N - 4 - base));

    float a[4], bv[4];
    a[0] = af4.x + ar4.w;  a[1] = af4.y + ar4.z;
    a[2] = af4.z + ar4.y;  a[3] = af4.w + ar4.x;
    bv[0] = bf4.x + br4.w; bv[1] = bf4.y + br4.z;
    bv[2] = bf4.z + br4.y; bv[3] = bf4.w + br4.x;

    float sa = 0.f, sb = 0.f;
    #pragma unroll
    for (int c = 0; c < 4; ++c) { sa += a[c]; sb += bv[c]; }

    // wave-64 inclusive shuffle scan of per-thread sums
    float va = sa, vb = sb;
    #pragma unroll
    for (int off = 1; off < 64; off <<= 1) {
        const float ua = __shfl_up(va, off, 64);
        const float ub = __shfl_up(vb, off, 64);
        if (lane >= off) { va += ua; vb += ub; }
    }
    if (lane == 63) { sWA[wv] = va; sWB[wv] = vb; }
    __syncthreads();

    float TA = 0.f, TB = 0.f, wpA = 0.f, wpB = 0.f;
    #pragma unroll
    for (int w2 = 0; w2 < 16; ++w2) {
        const float xa = sWA[w2];
        const float xb = sWB[w2];
        TA += xa; TB += xb;
        if (w2 < wv) { wpA += xa; wpB += xb; }
    }
    const float exA = wpA + (va - sa);
    const float exB = wpB + (vb - sb);

    float runA = 0.f, runB = 0.f;
    float logsum = 0.f;
    #pragma unroll
    for (int c = 0; c < 4; ++c) {
        const int i = base + c;
        const float E = TA - exA - runA;
        const float G = TB - exB - runB;
        runA += a[c];
        runB += bv[c];
        float denom = E * G - (float)(N - 2 * i);
        if (denom <= 0.f) denom = 1e-8f;
        logsum += __logf(denom);
    }

    // out = sum(log) - F ; threads 0..255 fold in -part[t]
    double lsum = (double)logsum - ((t < 256) ? part[t] : 0.0);
    #pragma unroll
    for (int off = 32; off > 0; off >>= 1)
        lsum += __shfl_xor(lsum, off, 64);
    if (lane == 0) sL[wv] = lsum;
    __syncthreads();
    if (t == 0) {
        double tot = 0.0;
        #pragma unroll
        for (int w2 = 0; w2 < 16; ++w2) tot += sL[w2];
        out[0] = (float)tot;
    }
}

extern "C" void kernel_launch(void* const* d_in, const int* in_sizes, int n_in,
                              void* d_out, int out_size, void* d_ws, size_t ws_size,
                              hipStream_t stream)
{
    const float* pred   = (const float*)d_in[0];
    const float* target = (const float*)d_in[1];
    float* out = (float*)d_out;
    float* ws  = (float*)d_ws;

    rank_kernel<<<256, 256, 0, stream>>>(pred, target, ws);
    loss_kernel<<<1, 1024, 0, stream>>>(ws, out);
}

// Round 5
// 22.899 us; speedup vs baseline: 1.3707x; 1.3707x over previous
//
#include <hip/hip_runtime.h>
#include <math.h>

#define N 8192
#define NP 4096

// Monotone total-order key for floats: s = bits ^ (sign ? 0xFFFFFFFF : 0x80000000).
// Full key K = (s << 13) | (8191 - k): K_k > K_j  <=>  t_k > t_j || (t_k == t_j && k < j),
// which is exactly the stable descending-argsort rank predicate.
__device__ __forceinline__ unsigned int fkey(float x) {
    unsigned int u = __float_as_uint(x);
    unsigned int m = (unsigned int)((int)u >> 31) | 0x80000000u;
    return u ^ m;
}

__device__ __forceinline__ unsigned long long fullkey(float x, int k) {
    return ((unsigned long long)fkey(x) << 13) | (unsigned long long)(N - 1 - k);
}

// Kernel 1: rank via ballot+popcount. 1024 waves, each owns 8 consecutive j's.
// Per iteration a wave covers 256 k's (float4 per lane); one v_cmp_gt_u64 + ballot
// counts 64 (j,k) pairs. Scatter pred[j] -> fsorted[rank_j].
__global__ void __launch_bounds__(256) rank_kernel(
    const float* __restrict__ pred,
    const float* __restrict__ target,
    float* __restrict__ fsorted)
{
    const int wid  = (blockIdx.x * blockDim.x + threadIdx.x) >> 6;  // 0..1023
    const int lane = threadIdx.x & 63;
    const int jbase = wid * 8;

    // wave-uniform keys for the 8 owned j's (scalar loads / SALU)
    unsigned long long Kj[8];
    #pragma unroll
    for (int jj = 0; jj < 8; ++jj)
        Kj[jj] = fullkey(target[jbase + jj], jbase + jj);

    int cnt[8] = {0, 0, 0, 0, 0, 0, 0, 0};

    #pragma unroll 2
    for (int it = 0; it < N / 256; ++it) {
        const int kb = it * 256 + lane * 4;
        const float4 tv = *reinterpret_cast<const float4*>(target + kb);
        unsigned long long Kk[4];
        Kk[0] = fullkey(tv.x, kb + 0);
        Kk[1] = fullkey(tv.y, kb + 1);
        Kk[2] = fullkey(tv.z, kb + 2);
        Kk[3] = fullkey(tv.w, kb + 3);
        #pragma unroll
        for (int jj = 0; jj < 8; ++jj) {
            cnt[jj] += __popcll(__ballot(Kk[0] > Kj[jj]));
            cnt[jj] += __popcll(__ballot(Kk[1] > Kj[jj]));
            cnt[jj] += __popcll(__ballot(Kk[2] > Kj[jj]));
            cnt[jj] += __popcll(__ballot(Kk[3] > Kj[jj]));
        }
    }

    #pragma unroll
    for (int jj = 0; jj < 8; ++jj) {
        if (lane == jj) fsorted[cnt[jj]] = pred[jbase + jj];
    }
}

// Kernel 2: closed-form loss from sorted f, fp32 with shuffle-scan.
//   a_i = e^{f_i} + e^{f_{N-1-i}},  b_i = e^{-f_i} + e^{-f_{N-1-i}}
//   E_i, G_i = suffix sums;  denom_i = E_i*G_i - (N - 2i)  (>= 2, no cancellation)
//   loss = - sum_i [ (f_i - f_{N-1-i}) - log(denom_i) ]
__global__ void __launch_bounds__(1024) loss_kernel(
    const float* __restrict__ f,
    float* __restrict__ out)
{
    __shared__ float sWA[16], sWB[16];
    __shared__ double sL[16];

    const int t    = threadIdx.x;
    const int lane = t & 63;
    const int w    = t >> 6;

    const float4 fi4 = *reinterpret_cast<const float4*>(f + 4 * t);
    const float4 fo4 = *reinterpret_cast<const float4*>(f + (N - 4 - 4 * t));
    float fi[4] = {fi4.x, fi4.y, fi4.z, fi4.w};
    float fo[4] = {fo4.w, fo4.z, fo4.y, fo4.x};   // reversed

    float a[4], b[4];
    float sa = 0.f, sb = 0.f;
    #pragma unroll
    for (int c = 0; c < 4; ++c) {
        const float e1 = __expf(fi[c]);
        const float e2 = __expf(fo[c]);
        const float m1 = __frcp_rn(e1);
        const float m2 = __frcp_rn(e2);
        a[c] = e1 + e2;
        b[c] = m1 + m2;
        sa += a[c];
        sb += b[c];
    }

    // wave-64 inclusive shuffle scan of per-thread sums
    float va = sa, vb = sb;
    #pragma unroll
    for (int off = 1; off < 64; off <<= 1) {
        const float ua = __shfl_up(va, off, 64);
        const float ub = __shfl_up(vb, off, 64);
        if (lane >= off) { va += ua; vb += ub; }
    }
    if (lane == 63) { sWA[w] = va; sWB[w] = vb; }
    __syncthreads();

    // totals + exclusive prefix of wave sums (16 broadcast LDS reads)
    float TA = 0.f, TB = 0.f, wpA = 0.f, wpB = 0.f;
    #pragma unroll
    for (int ww = 0; ww < 16; ++ww) {
        const float xa = sWA[ww];
        const float xb = sWB[ww];
        TA += xa; TB += xb;
        if (ww < w) { wpA += xa; wpB += xb; }
    }
    const float exA = wpA + (va - sa);   // sum of a over elements before this thread's chunk
    const float exB = wpB + (vb - sb);

    float runA = 0.f, runB = 0.f;
    double lsum = 0.0;
    #pragma unroll
    for (int c = 0; c < 4; ++c) {
        const int i = 4 * t + c;
        const float E = TA - exA - runA;    // suffix sum starting at i
        const float G = TB - exB - runB;
        runA += a[c];
        runB += b[c];
        float denom = E * G - (float)(N - 2 * i);
        if (denom <= 0.f) denom = 1e-8f;
        lsum += (double)(fi[c] - fo[c]) - (double)__logf(denom);
    }

    // block reduce
    #pragma unroll
    for (int off = 32; off > 0; off >>= 1)
        lsum += __shfl_down(lsum, off, 64);
    if (lane == 0) sL[w] = lsum;
    __syncthreads();
    if (t == 0) {
        double tot = 0.0;
        #pragma unroll
        for (int ww = 0; ww < 16; ++ww) tot += sL[ww];
        out[0] = (float)(-tot);
    }
}

extern "C" void kernel_launch(void* const* d_in, const int* in_sizes, int n_in,
                              void* d_out, int out_size, void* d_ws, size_t ws_size,
                              hipStream_t stream)
{
    const float* pred   = (const float*)d_in[0];
    const float* target = (const float*)d_in[1];
    float* out = (float*)d_out;
    float* fsorted = (float*)d_ws;   // 32 KB scratch

    rank_kernel<<<256, 256, 0, stream>>>(pred, target, fsorted);
    loss_kernel<<<1, 1024, 0, stream>>>(fsorted, out);
}